// Round 1
// baseline (223.825 us; speedup 1.0000x reference)
//
#include <hip/hip_runtime.h>

// CrossAttention: B=2, Lq=Lkv=2048, E=1024, H=16, D=64
// Pipeline: cvt(f32->bf16) x6 -> gemm Q,K (plain bf16 [M][E]) -> gemm V (transposed [B][H][D][Lkv])
//           -> flash attention -> gemm O (f32 out)

typedef unsigned short u16;
typedef unsigned int u32;
typedef __attribute__((ext_vector_type(4))) float f32x4;
typedef __attribute__((ext_vector_type(8))) short s16x8;
typedef __attribute__((ext_vector_type(4))) u16 u16x4;

#define LOG2E 1.44269504088896f

__device__ __forceinline__ u16 f2bf(float f) {
  u32 u = __builtin_bit_cast(u32, f);
  u += 0x7FFFu + ((u >> 16) & 1u);
  return (u16)(u >> 16);
}

typedef const __attribute__((address_space(1))) u32 GAS;
typedef __attribute__((address_space(3))) u32 LAS;

// async global->LDS, 16B per lane; LDS dest = wave-uniform base + lane*16
__device__ __forceinline__ void g2l16(const u16* g, u16* l) {
  __builtin_amdgcn_global_load_lds((GAS*)g, (LAS*)l, 16, 0, 0);
}

__global__ void cvt_bf16(const float* __restrict__ src, u16* __restrict__ dst, int n4) {
  int i = blockIdx.x * blockDim.x + threadIdx.x;
  if (i >= n4) return;
  f32x4 v = ((const f32x4*)src)[i];
  u16x4 o;
  o[0] = f2bf(v[0]); o[1] = f2bf(v[1]); o[2] = f2bf(v[2]); o[3] = f2bf(v[3]);
  ((u16x4*)dst)[i] = o;
}

// C[m][n] = sum_k A[m][k] * W[n][k] + bias[n].  M=4096, N=1024, K=1024.
// MODE 0: out bf16 plain [M][1024]   (Q, K)
// MODE 1: out bf16 scatter [B][H][D][2048]  (V transposed)
// MODE 2: out f32 plain [M][1024]    (final O)
template <int MODE>
__global__ __launch_bounds__(256, 2) void gemm_bt(const u16* __restrict__ A,
                                                  const u16* __restrict__ W,
                                                  const float* __restrict__ bias,
                                                  void* __restrict__ out) {
  constexpr int K = 1024;
  __shared__ u16 As[128 * 64];
  __shared__ u16 Bs[128 * 64];
  const int tid = threadIdx.x;
  const int w = tid >> 6;
  const int lane = tid & 63;
  const int wr = w >> 1, wc = w & 1;
  const int m0 = blockIdx.y * 128;
  const int n0 = blockIdx.x * 128;
  const int l15 = lane & 15, l4 = lane >> 4;
  const int srow = lane >> 3, sslot = lane & 7;

  f32x4 acc[4][4];
#pragma unroll
  for (int m = 0; m < 4; ++m)
#pragma unroll
    for (int n = 0; n < 4; ++n) acc[m][n] = (f32x4){0.f, 0.f, 0.f, 0.f};

  for (int k0 = 0; k0 < K; k0 += 64) {
    __syncthreads();
#pragma unroll
    for (int it = 0; it < 4; ++it) {
      const int rbase = w * 32 + it * 8;           // wave-uniform
      const int r = rbase + srow;
      const int ca = ((sslot ^ (r & 7)) << 3);     // pre-swizzled source col (m173)
      g2l16(A + (size_t)(m0 + r) * K + k0 + ca, &As[rbase * 64]);
      g2l16(W + (size_t)(n0 + r) * K + k0 + ca, &Bs[rbase * 64]);
    }
    __syncthreads();

    s16x8 af[4][2], bf[4][2];
#pragma unroll
    for (int m = 0; m < 4; ++m) {
      const int row = wr * 64 + m * 16 + l15;
#pragma unroll
      for (int kk = 0; kk < 2; ++kk) {
        const int slot = (kk * 4 + l4) ^ (row & 7);
        af[m][kk] = *(const s16x8*)&As[row * 64 + slot * 8];
      }
    }
#pragma unroll
    for (int n = 0; n < 4; ++n) {
      const int row = wc * 64 + n * 16 + l15;
#pragma unroll
      for (int kk = 0; kk < 2; ++kk) {
        const int slot = (kk * 4 + l4) ^ (row & 7);
        bf[n][kk] = *(const s16x8*)&Bs[row * 64 + slot * 8];
      }
    }
#pragma unroll
    for (int m = 0; m < 4; ++m)
#pragma unroll
      for (int n = 0; n < 4; ++n)
#pragma unroll
        for (int kk = 0; kk < 2; ++kk)
          acc[m][n] = __builtin_amdgcn_mfma_f32_16x16x32_bf16(af[m][kk], bf[n][kk],
                                                              acc[m][n], 0, 0, 0);
  }

#pragma unroll
  for (int n = 0; n < 4; ++n) {
    const int col = n0 + wc * 64 + n * 16 + l15;
    const float bv = bias[col];
#pragma unroll
    for (int m = 0; m < 4; ++m) {
      const int rowb = m0 + wr * 64 + m * 16 + l4 * 4;
#pragma unroll
      for (int j = 0; j < 4; ++j) {
        const float v = acc[m][n][j] + bv;
        const int row = rowb + j;
        if (MODE == 2) {
          ((float*)out)[(size_t)row * 1024 + col] = v;
        } else if (MODE == 0) {
          ((u16*)out)[(size_t)row * 1024 + col] = f2bf(v);
        } else {
          const int b = row >> 11, r = row & 2047;
          const int h = col >> 6, d = col & 63;
          ((u16*)out)[(((size_t)(b * 16 + h) * 64) + d) * 2048 + r] = f2bf(v);
        }
      }
    }
  }
}

// Flash attention. Block = 4 waves, 64 q-rows (16/wave). KV tiles of 64.
// Qp/Kp: bf16 [B*2048][1024] (col = h*64+d). Vt: bf16 [B*16][64][2048]. ctx: bf16 [B*2048][1024].
__global__ __launch_bounds__(256, 2) void attn_fwd(const u16* __restrict__ Qp,
                                                   const u16* __restrict__ Kp,
                                                   const u16* __restrict__ Vt,
                                                   const int* __restrict__ mask,
                                                   u16* __restrict__ ctx) {
  __shared__ u16 Ks[64 * 64];
  __shared__ u16 Vs[64 * 64];
  __shared__ float mb[64];
  __shared__ u16 Ps[4][16][72];   // per-wave P, padded to 72 (144B rows, 16B-aligned)
  const int tid = threadIdx.x;
  const int w = tid >> 6;
  const int lane = tid & 63;
  const int l15 = lane & 15, l4 = lane >> 4;
  const int q0 = blockIdx.x * 64;
  const int h = blockIdx.y;
  const int b = blockIdx.z;
  const int srow = lane >> 3, sslot = lane & 7;

  // Q fragments (A operand): lane holds Q[q0+w*16+l15][l4*8 + i (+32)]
  const u16* qptr = Qp + ((size_t)(b * 2048 + q0 + w * 16 + l15)) * 1024 + h * 64 + l4 * 8;
  const s16x8 qf0 = *(const s16x8*)qptr;
  const s16x8 qf1 = *(const s16x8*)(qptr + 32);

  float m_run[4], l_run[4];
  f32x4 acc[4];
#pragma unroll
  for (int j = 0; j < 4; ++j) { m_run[j] = -__builtin_inff(); l_run[j] = 0.f; }
#pragma unroll
  for (int n = 0; n < 4; ++n) acc[n] = (f32x4){0.f, 0.f, 0.f, 0.f};

  for (int kv0 = 0; kv0 < 2048; kv0 += 64) {
    __syncthreads();
#pragma unroll
    for (int it = 0; it < 2; ++it) {
      const int rbase = w * 16 + it * 8;           // wave-uniform
      const int r = rbase + srow;
      const int ca = ((sslot ^ (r & 7)) << 3);
      g2l16(Kp + (size_t)(b * 2048 + kv0 + r) * 1024 + h * 64 + ca, &Ks[rbase * 64]);
      g2l16(Vt + ((size_t)((b * 16 + h) * 64 + r)) * 2048 + kv0 + ca, &Vs[rbase * 64]);
    }
    if (tid < 64) mb[tid] = (mask[b * 2048 + kv0 + tid] == 0) ? -1e30f : 0.f;
    __syncthreads();

    // S = Q K^T  (rows q, cols kv)
    f32x4 s[4];
#pragma unroll
    for (int n = 0; n < 4; ++n) {
      s[n] = (f32x4){0.f, 0.f, 0.f, 0.f};
      const int rb = n * 16 + l15;
#pragma unroll
      for (int kk = 0; kk < 2; ++kk) {
        const int slot = (kk * 4 + l4) ^ (rb & 7);
        const s16x8 kf = *(const s16x8*)&Ks[rb * 64 + slot * 8];
        s[n] = __builtin_amdgcn_mfma_f32_16x16x32_bf16(kk == 0 ? qf0 : qf1, kf, s[n], 0, 0, 0);
      }
    }
    float mbv[4];
#pragma unroll
    for (int n = 0; n < 4; ++n) mbv[n] = mb[n * 16 + l15];

#pragma unroll
    for (int j = 0; j < 4; ++j) {
      float s0 = s[0][j] * 0.125f + mbv[0];
      float s1 = s[1][j] * 0.125f + mbv[1];
      float s2 = s[2][j] * 0.125f + mbv[2];
      float s3 = s[3][j] * 0.125f + mbv[3];
      float mx = fmaxf(fmaxf(s0, s1), fmaxf(s2, s3));
      mx = fmaxf(mx, __shfl_xor(mx, 1, 64));
      mx = fmaxf(mx, __shfl_xor(mx, 2, 64));
      mx = fmaxf(mx, __shfl_xor(mx, 4, 64));
      mx = fmaxf(mx, __shfl_xor(mx, 8, 64));
      const float mnew = fmaxf(m_run[j], mx);
      const float alpha = exp2f((m_run[j] - mnew) * LOG2E);
      m_run[j] = mnew;
      const float p0 = exp2f((s0 - mnew) * LOG2E);
      const float p1 = exp2f((s1 - mnew) * LOG2E);
      const float p2 = exp2f((s2 - mnew) * LOG2E);
      const float p3 = exp2f((s3 - mnew) * LOG2E);
      float ps = (p0 + p1) + (p2 + p3);
      ps += __shfl_xor(ps, 1, 64);
      ps += __shfl_xor(ps, 2, 64);
      ps += __shfl_xor(ps, 4, 64);
      ps += __shfl_xor(ps, 8, 64);
      l_run[j] = l_run[j] * alpha + ps;
#pragma unroll
      for (int n = 0; n < 4; ++n) acc[n][j] *= alpha;
      const int prow = l4 * 4 + j;
      Ps[w][prow][0 + l15] = f2bf(p0);
      Ps[w][prow][16 + l15] = f2bf(p1);
      Ps[w][prow][32 + l15] = f2bf(p2);
      Ps[w][prow][48 + l15] = f2bf(p3);
    }

    // acc += P V   (A = P from wave-private LDS, B from Vs rows = d)
#pragma unroll
    for (int kk = 0; kk < 2; ++kk) {
      const s16x8 pf = *(const s16x8*)&Ps[w][l15][kk * 32 + l4 * 8];
#pragma unroll
      for (int n = 0; n < 4; ++n) {
        const int rb = n * 16 + l15;
        const int slot = (kk * 4 + l4) ^ (rb & 7);
        const s16x8 vf = *(const s16x8*)&Vs[rb * 64 + slot * 8];
        acc[n] = __builtin_amdgcn_mfma_f32_16x16x32_bf16(pf, vf, acc[n], 0, 0, 0);
      }
    }
  }

#pragma unroll
  for (int j = 0; j < 4; ++j) {
    const float inv = 1.f / l_run[j];
    const int row = q0 + w * 16 + l4 * 4 + j;
#pragma unroll
    for (int n = 0; n < 4; ++n) {
      const int col = h * 64 + n * 16 + l15;
      ctx[((size_t)(b * 2048 + row)) * 1024 + col] = f2bf(acc[n][j] * inv);
    }
  }
}

extern "C" void kernel_launch(void* const* d_in, const int* in_sizes, int n_in,
                              void* d_out, int out_size, void* d_ws, size_t ws_size,
                              hipStream_t stream) {
  const float* query = (const float*)d_in[0];
  const float* keyv  = (const float*)d_in[1];
  const int*   mask  = (const int*)d_in[2];
  const float* Wq = (const float*)d_in[3];
  const float* bq = (const float*)d_in[4];
  const float* Wk = (const float*)d_in[5];
  const float* bk = (const float*)d_in[6];
  const float* Wv = (const float*)d_in[7];
  const float* bv = (const float*)d_in[8];
  const float* Wo = (const float*)d_in[9];
  const float* bo = (const float*)d_in[10];

  const size_t NTOK = (size_t)4096 * 1024;  // B*L x E
  const size_t NW = (size_t)1024 * 1024;    // E x E
  u16* p = (u16*)d_ws;
  u16* qb  = p; p += NTOK;
  u16* kvb = p; p += NTOK;
  u16* wqb = p; p += NW;
  u16* wkb = p; p += NW;
  u16* wvb = p; p += NW;
  u16* wob = p; p += NW;
  u16* Qp  = p; p += NTOK;
  u16* Kp  = p; p += NTOK;
  u16* Vt  = p; p += NTOK;
  u16* ctx = p; p += NTOK;

  cvt_bf16<<<4096, 256, 0, stream>>>(query, qb, (int)(NTOK / 4));
  cvt_bf16<<<4096, 256, 0, stream>>>(keyv, kvb, (int)(NTOK / 4));
  cvt_bf16<<<1024, 256, 0, stream>>>(Wq, wqb, (int)(NW / 4));
  cvt_bf16<<<1024, 256, 0, stream>>>(Wk, wkb, (int)(NW / 4));
  cvt_bf16<<<1024, 256, 0, stream>>>(Wv, wvb, (int)(NW / 4));
  cvt_bf16<<<1024, 256, 0, stream>>>(Wo, wob, (int)(NW / 4));

  dim3 gg(8, 32);  // N/128, M/128
  gemm_bt<0><<<gg, 256, 0, stream>>>(qb,  wqb, bq, Qp);
  gemm_bt<0><<<gg, 256, 0, stream>>>(kvb, wkb, bk, Kp);
  gemm_bt<1><<<gg, 256, 0, stream>>>(kvb, wvb, bv, Vt);
  attn_fwd<<<dim3(32, 16, 2), 256, 0, stream>>>(Qp, Kp, Vt, mask, ctx);
  gemm_bt<2><<<gg, 256, 0, stream>>>(ctx, wob, bo, (float*)d_out);
}

// Round 2
// 148.738 us; speedup vs baseline: 1.5048x; 1.5048x over previous
//
#include <hip/hip_runtime.h>

// CrossAttention B=2, L=2048, E=1024, H=16, D=64
// cvt_tok + cvt_w -> fused QKV proj gemm (8-wave 128x128) -> attn (32x32 swapped MFMA,
// in-reg softmax, cvt_pk+permlane P, defer-max) -> O gemm (f32 out)

typedef unsigned short u16;
typedef unsigned int u32;
typedef __attribute__((ext_vector_type(4))) float f32x4;
typedef __attribute__((ext_vector_type(16))) float f32x16;
typedef __attribute__((ext_vector_type(8))) short s16x8;
typedef __attribute__((ext_vector_type(4))) u16 u16x4;
typedef __attribute__((ext_vector_type(4))) u32 u32x4;

#define C_SCALE 0.18033688011112042f  // 0.125 * log2(e)
#define NEGBIG -30000.0f
#define THR2 11.54f                   // defer-max threshold (log2 domain, ~8 nats)

__device__ __forceinline__ u16 f2bf(float f) {
  u32 u = __builtin_bit_cast(u32, f);
  u += 0x7FFFu + ((u >> 16) & 1u);
  return (u16)(u >> 16);
}

typedef const __attribute__((address_space(1))) u32 GAS;
typedef __attribute__((address_space(3))) u32 LAS;
__device__ __forceinline__ void g2l16(const u16* g, u16* l) {
  __builtin_amdgcn_global_load_lds((GAS*)g, (LAS*)l, 16, 0, 0);
}
__device__ __forceinline__ void g2l4(const float* g, float* l) {
  __builtin_amdgcn_global_load_lds((GAS*)g, (LAS*)l, 4, 0, 0);
}

__device__ __forceinline__ f32x16 z16() {
  f32x16 v;
#pragma unroll
  for (int i = 0; i < 16; ++i) v[i] = 0.f;
  return v;
}

// ---------------- conversions ----------------
__global__ void cvt_tok(const float* __restrict__ q, u16* __restrict__ qb,
                        const float* __restrict__ kv, u16* __restrict__ kvb,
                        const int* __restrict__ mask, float* __restrict__ madd2) {
  const int tid = threadIdx.x;
  const float* s = blockIdx.y ? kv : q;
  u16* d = blockIdx.y ? kvb : qb;
  const int i = blockIdx.x * 256 + tid;
  f32x4 v = ((const f32x4*)s)[i];
  u16x4 o;
  o[0] = f2bf(v[0]); o[1] = f2bf(v[1]); o[2] = f2bf(v[2]); o[3] = f2bf(v[3]);
  ((u16x4*)d)[i] = o;
  if (blockIdx.y == 0 && blockIdx.x < 16) {
    const int mi = blockIdx.x * 256 + tid;  // 4096 mask entries
    madd2[mi] = mask[mi] ? 0.f : NEGBIG;
  }
}

__global__ void cvt_w(const float* __restrict__ w0, u16* __restrict__ o0,
                      const float* __restrict__ w1, u16* __restrict__ o1,
                      const float* __restrict__ w2, u16* __restrict__ o2,
                      const float* __restrict__ w3, u16* __restrict__ o3) {
  const int y = blockIdx.y;
  const float* s = y == 0 ? w0 : y == 1 ? w1 : y == 2 ? w2 : w3;
  u16* d = y == 0 ? o0 : y == 1 ? o1 : y == 2 ? o2 : o3;
  const int i = blockIdx.x * 256 + threadIdx.x;
  f32x4 v = ((const f32x4*)s)[i];
  u16x4 o;
  o[0] = f2bf(v[0]); o[1] = f2bf(v[1]); o[2] = f2bf(v[2]); o[3] = f2bf(v[3]);
  ((u16x4*)d)[i] = o;
}

// ---------------- GEMM: C = A @ W^T + bias, M=4096 N=1024 K=1024 ----------------
// 8 waves, 128x128 tile, BK=64. mode 0: bf16 [M][1024]; mode 1: bf16 V-transpose
// [B*16][64][2048] via LDS transpose; mode 2: f32 [M][1024].
struct Jobs {
  const u16* A[3];
  const u16* W[3];
  const float* bias[3];
  void* out[3];
  int mode[3];
};

__global__ __launch_bounds__(512, 2) void gemm8(Jobs jb) {
  const int z = blockIdx.z;
  const u16* __restrict__ A = jb.A[z];
  const u16* __restrict__ W = jb.W[z];
  const float* __restrict__ bias = jb.bias[z];
  void* __restrict__ out = jb.out[z];
  const int mode = jb.mode[z];

  __shared__ u16 smem[16384];  // As[128*64] | Bs[128*64]; reused as T[128][128]
  u16* As = smem;
  u16* Bs = smem + 8192;
  const int tid = threadIdx.x;
  const int w = tid >> 6, lane = tid & 63;
  const int wr = w >> 1, wc = w & 1;
  const int m0 = blockIdx.y * 128, n0 = blockIdx.x * 128;
  const int l15 = lane & 15, l4 = lane >> 4;
  const int srow = lane >> 3, sslot = lane & 7;

  f32x4 acc[2][4];
#pragma unroll
  for (int m = 0; m < 2; ++m)
#pragma unroll
    for (int n = 0; n < 4; ++n) acc[m][n] = (f32x4){0.f, 0.f, 0.f, 0.f};

  for (int k0 = 0; k0 < 1024; k0 += 64) {
    __syncthreads();
#pragma unroll
    for (int it = 0; it < 4; ++it) {
      const int rbase = (w & 3) * 32 + it * 8;
      const int r = rbase + srow;
      const int ca = ((sslot ^ (r & 7)) << 3);
      if (w < 4) g2l16(A + (size_t)(m0 + r) * 1024 + k0 + ca, &As[rbase * 64]);
      else       g2l16(W + (size_t)(n0 + r) * 1024 + k0 + ca, &Bs[rbase * 64]);
    }
    __syncthreads();

    s16x8 af[2][2], bf[4][2];
#pragma unroll
    for (int m = 0; m < 2; ++m) {
      const int row = wr * 32 + m * 16 + l15;
#pragma unroll
      for (int kk = 0; kk < 2; ++kk) {
        const int slot = (kk * 4 + l4) ^ (row & 7);
        af[m][kk] = *(const s16x8*)&As[row * 64 + slot * 8];
      }
    }
#pragma unroll
    for (int n = 0; n < 4; ++n) {
      const int row = wc * 64 + n * 16 + l15;
#pragma unroll
      for (int kk = 0; kk < 2; ++kk) {
        const int slot = (kk * 4 + l4) ^ (row & 7);
        bf[n][kk] = *(const s16x8*)&Bs[row * 64 + slot * 8];
      }
    }
#pragma unroll
    for (int m = 0; m < 2; ++m)
#pragma unroll
      for (int n = 0; n < 4; ++n)
#pragma unroll
        for (int kk = 0; kk < 2; ++kk)
          acc[m][n] = __builtin_amdgcn_mfma_f32_16x16x32_bf16(af[m][kk], bf[n][kk],
                                                              acc[m][n], 0, 0, 0);
  }

  if (mode != 1) {
#pragma unroll
    for (int n = 0; n < 4; ++n) {
      const int col = n0 + wc * 64 + n * 16 + l15;
      const float bv = bias[col];
#pragma unroll
      for (int m = 0; m < 2; ++m) {
        const int rowb = m0 + wr * 32 + m * 16 + l4 * 4;
#pragma unroll
        for (int j = 0; j < 4; ++j) {
          const float v = acc[m][n][j] + bv;
          if (mode == 2) ((float*)out)[(size_t)(rowb + j) * 1024 + col] = v;
          else           ((u16*)out)[(size_t)(rowb + j) * 1024 + col] = f2bf(v);
        }
      }
    }
  } else {
    // V: transpose tile via LDS, write Vt[(b*16+h)*64+d][2048]
    __syncthreads();
    u16* T = smem;  // [128 cols][128 rows]
#pragma unroll
    for (int n = 0; n < 4; ++n) {
      const int col = wc * 64 + n * 16 + l15;
      const float bv = bias[n0 + col];
#pragma unroll
      for (int m = 0; m < 2; ++m) {
        const int rowb = wr * 32 + m * 16 + l4 * 4;
        u16x4 v;
#pragma unroll
        for (int j = 0; j < 4; ++j) v[j] = f2bf(acc[m][n][j] + bv);
        *(u16x4*)&T[col * 128 + (rowb ^ ((col & 7) * 8))] = v;
      }
    }
    __syncthreads();
    u16* Vt = (u16*)out;
#pragma unroll
    for (int pass = 0; pass < 4; ++pass) {
      const int c = pass * 32 + (tid >> 4);
      const int slot = tid & 15;
      const s16x8 v = *(const s16x8*)&T[c * 128 + ((slot * 8) ^ ((c & 7) * 8))];
      const int cg = n0 + c, h = cg >> 6, d = cg & 63;
      const int rg = m0 + slot * 8, b = rg >> 11, rr = rg & 2047;
      *(s16x8*)&Vt[(((size_t)(b * 16 + h) * 64) + d) * 2048 + rr] = v;
    }
  }
}

// ---------------- Flash attention, 32x32 swapped MFMA ----------------
// 4 waves/block, 32 q-rows/wave (128/block). KV tile = 64.
// Qp/Kp: bf16 [B*2048][1024]; Vt: bf16 [B*16][64][2048]; madd2: f32 [B*2048] (log2-domain)
__global__ __launch_bounds__(256, 2) void attn_fwd(const u16* __restrict__ Qp,
                                                   const u16* __restrict__ Kp,
                                                   const u16* __restrict__ Vt,
                                                   const float* __restrict__ madd2,
                                                   u16* __restrict__ ctx) {
  __shared__ u16 smem[8192];  // Ks[64][64] | Vs[64][64]; reused as per-wave Ot[32][64]
  __shared__ float mb[64];
  u16* Ks = smem;
  u16* Vs = smem + 4096;
  const int tid = threadIdx.x;
  const int w = tid >> 6, lane = tid & 63;
  const int l31 = lane & 31, h5 = lane >> 5;
  const int q0 = blockIdx.x * 128;
  const int head = blockIdx.y, b = blockIdx.z;
  const int srow = lane >> 3, sslot = lane & 7;

  // Q fragments (B operand): lane holds Q[q=q0+w*32+l31][head*64 + kstep*16 + h5*8 + i]
  const u16* qbase = Qp + ((size_t)(b * 2048 + q0 + w * 32 + l31)) * 1024 + head * 64 + h5 * 8;
  s16x8 qf[4];
#pragma unroll
  for (int k = 0; k < 4; ++k) qf[k] = *(const s16x8*)(qbase + k * 16);

  f32x16 oa = z16(), ob = z16();
  float m2 = -__builtin_inff(), l_run = 0.f;

  for (int kv0 = 0; kv0 < 2048; kv0 += 64) {
    __syncthreads();
#pragma unroll
    for (int it = 0; it < 2; ++it) {
      const int rbase = w * 16 + it * 8;
      const int r = rbase + srow;
      const int ca = ((sslot ^ (r & 7)) << 3);
      g2l16(Kp + (size_t)(b * 2048 + kv0 + r) * 1024 + head * 64 + ca, &Ks[rbase * 64]);
      g2l16(Vt + (((size_t)(b * 16 + head) * 64) + r) * 2048 + kv0 + ca, &Vs[rbase * 64]);
    }
    if (w == 0) g2l4(madd2 + b * 2048 + kv0 + lane, mb);
    __syncthreads();

    // S^T = K Q^T : A=K rows kv, B=Q cols q. Lane: q=l31; kv=(r&3)+8*(r>>2)+4*h5 (+32 for s1)
    f32x16 s0 = z16(), s1 = z16();
#pragma unroll
    for (int ks = 0; ks < 4; ++ks) {
      const int cu = (ks * 16 + h5 * 8) ^ ((l31 & 7) * 8);
      const s16x8 kf0 = *(const s16x8*)&Ks[l31 * 64 + cu];
      const s16x8 kf1 = *(const s16x8*)&Ks[(32 + l31) * 64 + cu];
      s0 = __builtin_amdgcn_mfma_f32_32x32x16_bf16(kf0, qf[ks], s0, 0, 0, 0);
      s1 = __builtin_amdgcn_mfma_f32_32x32x16_bf16(kf1, qf[ks], s1, 0, 0, 0);
    }

    // u = s*scale*log2e + mask (log2 domain)
    f32x4 mk0[4], mk1[4];
#pragma unroll
    for (int g = 0; g < 4; ++g) {
      mk0[g] = *(const f32x4*)&mb[g * 8 + h5 * 4];
      mk1[g] = *(const f32x4*)&mb[32 + g * 8 + h5 * 4];
    }
    float u[32];
#pragma unroll
    for (int g = 0; g < 4; ++g)
#pragma unroll
      for (int e = 0; e < 4; ++e) {
        u[g * 4 + e] = fmaf(s0[g * 4 + e], C_SCALE, mk0[g][e]);
        u[16 + g * 4 + e] = fmaf(s1[g * 4 + e], C_SCALE, mk1[g][e]);
      }

    // row max: in-lane tree over 32 + one cross-half exchange
    float t[16];
#pragma unroll
    for (int i = 0; i < 16; ++i) t[i] = fmaxf(u[i], u[i + 16]);
#pragma unroll
    for (int i = 0; i < 8; ++i) t[i] = fmaxf(t[i], t[i + 8]);
#pragma unroll
    for (int i = 0; i < 4; ++i) t[i] = fmaxf(t[i], t[i + 4]);
    float mx = fmaxf(fmaxf(t[0], t[1]), fmaxf(t[2], t[3]));
    mx = fmaxf(mx, __shfl_xor(mx, 32, 64));

    // defer-max rescale
    if (__any(mx > m2 + THR2)) {
      const float mnew = fmaxf(m2, mx);
      const float alpha = exp2f(m2 - mnew);
      m2 = mnew;
      l_run *= alpha;
#pragma unroll
      for (int i = 0; i < 16; ++i) { oa[i] *= alpha; ob[i] *= alpha; }
    }

    float p[32];
#pragma unroll
    for (int i = 0; i < 32; ++i) p[i] = exp2f(u[i] - m2);

    float st[16];
#pragma unroll
    for (int i = 0; i < 16; ++i) st[i] = p[i] + p[i + 16];
#pragma unroll
    for (int i = 0; i < 8; ++i) st[i] += st[i + 8];
#pragma unroll
    for (int i = 0; i < 4; ++i) st[i] += st[i + 4];
    float ps = (st[0] + st[1]) + (st[2] + st[3]);
    ps += __shfl_xor(ps, 32, 64);
    l_run += ps;

    // P -> bf16 B-fragments via cvt_pk + permlane32_swap (T12)
    u32 pk[16];
#pragma unroll
    for (int kvb = 0; kvb < 2; ++kvb)
#pragma unroll
      for (int g = 0; g < 4; ++g)
#pragma unroll
        for (int e2 = 0; e2 < 2; ++e2) {
          u32 d;
          asm("v_cvt_pk_bf16_f32 %0, %1, %2"
              : "=v"(d)
              : "v"(p[kvb * 16 + g * 4 + e2 * 2]), "v"(p[kvb * 16 + g * 4 + e2 * 2 + 1]));
          pk[kvb * 8 + g * 2 + e2] = d;
        }
    s16x8 pf[4];
#pragma unroll
    for (int kvb = 0; kvb < 2; ++kvb)
#pragma unroll
      for (int gp = 0; gp < 2; ++gp) {
        u32 a0 = pk[kvb * 8 + gp * 4 + 0], a1 = pk[kvb * 8 + gp * 4 + 1];
        u32 b0 = pk[kvb * 8 + gp * 4 + 2], b1 = pk[kvb * 8 + gp * 4 + 3];
        asm("v_permlane32_swap_b32 %0, %1" : "+v"(a0), "+v"(b0));
        asm("v_permlane32_swap_b32 %0, %1" : "+v"(a1), "+v"(b1));
        u32x4 fv; fv[0] = a0; fv[1] = a1; fv[2] = b0; fv[3] = b1;
        pf[kvb * 2 + gp] = __builtin_bit_cast(s16x8, fv);
      }

    // O^T += V^T P : A = Vt rows d, B = P cols q
#pragma unroll
    for (int ks = 0; ks < 4; ++ks) {
      const int cu = (ks * 16 + h5 * 8) ^ ((l31 & 7) * 8);
      const s16x8 vf0 = *(const s16x8*)&Vs[l31 * 64 + cu];
      const s16x8 vf1 = *(const s16x8*)&Vs[(32 + l31) * 64 + cu];
      oa = __builtin_amdgcn_mfma_f32_32x32x16_bf16(vf0, pf[ks], oa, 0, 0, 0);
      ob = __builtin_amdgcn_mfma_f32_32x32x16_bf16(vf1, pf[ks], ob, 0, 0, 0);
    }
  }

  // epilogue: normalize, transpose via wave-private LDS, coalesced stores
  const float inv = 1.f / l_run;
  u16* Ot = &smem[w * 2048];  // [32 q][64 d]
  __syncthreads();
#pragma unroll
  for (int dblk = 0; dblk < 2; ++dblk)
#pragma unroll
    for (int g = 0; g < 4; ++g) {
      u16x4 v;
#pragma unroll
      for (int e = 0; e < 4; ++e)
        v[e] = f2bf((dblk ? ob[g * 4 + e] : oa[g * 4 + e]) * inv);
      *(u16x4*)&Ot[l31 * 64 + ((dblk * 32 + g * 8 + h5 * 4) ^ ((l31 & 7) * 8))] = v;
    }
#pragma unroll
  for (int pass = 0; pass < 4; ++pass) {
    const int row = pass * 8 + srow;
    const s16x8 v = *(const s16x8*)&Ot[row * 64 + ((sslot * 8) ^ ((row & 7) * 8))];
    *(s16x8*)(ctx + ((size_t)(b * 2048 + q0 + w * 32 + row)) * 1024 + head * 64 + sslot * 8) = v;
  }
}

extern "C" void kernel_launch(void* const* d_in, const int* in_sizes, int n_in,
                              void* d_out, int out_size, void* d_ws, size_t ws_size,
                              hipStream_t stream) {
  const float* query = (const float*)d_in[0];
  const float* keyv = (const float*)d_in[1];
  const int* mask = (const int*)d_in[2];
  const float* Wq = (const float*)d_in[3];
  const float* bq = (const float*)d_in[4];
  const float* Wk = (const float*)d_in[5];
  const float* bk = (const float*)d_in[6];
  const float* Wv = (const float*)d_in[7];
  const float* bv = (const float*)d_in[8];
  const float* Wo = (const float*)d_in[9];
  const float* bo = (const float*)d_in[10];

  const size_t NTOK = (size_t)4096 * 1024;
  const size_t NW = (size_t)1024 * 1024;
  u16* p = (u16*)d_ws;
  u16* qb = p;  p += NTOK;
  u16* kvb = p; p += NTOK;
  u16* wqb = p; p += NW;
  u16* wkb = p; p += NW;
  u16* wvb = p; p += NW;
  u16* wob = p; p += NW;
  u16* Qp = p;  p += NTOK;
  u16* Kp = p;  p += NTOK;
  u16* Vt = p;  p += NTOK;
  u16* ctx = p; p += NTOK;
  float* madd2 = (float*)p;  // 4096 f32

  cvt_tok<<<dim3(4096, 2), 256, 0, stream>>>(query, qb, keyv, kvb, mask, madd2);
  cvt_w<<<dim3(1024, 4), 256, 0, stream>>>(Wq, wqb, Wk, wkb, Wv, wvb, Wo, wob);

  Jobs pj;
  pj.A[0] = qb;  pj.W[0] = wqb; pj.bias[0] = bq; pj.out[0] = Qp; pj.mode[0] = 0;
  pj.A[1] = kvb; pj.W[1] = wkb; pj.bias[1] = bk; pj.out[1] = Kp; pj.mode[1] = 0;
  pj.A[2] = kvb; pj.W[2] = wvb; pj.bias[2] = bv; pj.out[2] = Vt; pj.mode[2] = 1;
  gemm8<<<dim3(8, 32, 3), 512, 0, stream>>>(pj);

  attn_fwd<<<dim3(16, 16, 2), 256, 0, stream>>>(Qp, Kp, Vt, madd2, ctx);

  Jobs oj;
  oj.A[0] = ctx; oj.W[0] = wob; oj.bias[0] = bo; oj.out[0] = d_out; oj.mode[0] = 2;
  oj.A[1] = ctx; oj.W[1] = wob; oj.bias[1] = bo; oj.out[1] = d_out; oj.mode[1] = 2;
  oj.A[2] = ctx; oj.W[2] = wob; oj.bias[2] = bo; oj.out[2] = d_out; oj.mode[2] = 2;
  gemm8<<<dim3(8, 32, 1), 512, 0, stream>>>(oj);
}

// Round 3
// 133.734 us; speedup vs baseline: 1.6737x; 1.1122x over previous
//
#include <hip/hip_runtime.h>

// CrossAttention B=2, L=2048, E=1024, H=16, D=64
// cvt -> fused QKV gemm (8-wave 128x128, 2-phase dbuf) -> attn (32x32 swapped MFMA,
// packed-f32 softmax, dbuf K/V pipeline) -> O gemm (f32 out)

typedef unsigned short u16;
typedef unsigned int u32;
typedef __attribute__((ext_vector_type(2))) float f32x2;
typedef __attribute__((ext_vector_type(4))) float f32x4;
typedef __attribute__((ext_vector_type(16))) float f32x16;
typedef __attribute__((ext_vector_type(8))) short s16x8;
typedef __attribute__((ext_vector_type(4))) u16 u16x4;
typedef __attribute__((ext_vector_type(4))) u32 u32x4;

#define C_SCALE 0.18033688011112042f  // 0.125 * log2(e)
#define NEGBIG -30000.0f
#define THR2 11.54f                   // defer-max threshold (log2 domain)

__device__ __forceinline__ u16 f2bf(float f) {
  u32 u = __builtin_bit_cast(u32, f);
  u += 0x7FFFu + ((u >> 16) & 1u);
  return (u16)(u >> 16);
}

__device__ __forceinline__ float exp2_fast(float x) {
  float r;
  asm("v_exp_f32 %0, %1" : "=v"(r) : "v"(x));
  return r;
}

typedef const __attribute__((address_space(1))) u32 GAS;
typedef __attribute__((address_space(3))) u32 LAS;
__device__ __forceinline__ void g2l16(const u16* g, u16* l) {
  __builtin_amdgcn_global_load_lds((GAS*)g, (LAS*)l, 16, 0, 0);
}
__device__ __forceinline__ void g2l4(const float* g, float* l) {
  __builtin_amdgcn_global_load_lds((GAS*)g, (LAS*)l, 4, 0, 0);
}

__device__ __forceinline__ f32x16 z16() {
  f32x16 v;
#pragma unroll
  for (int i = 0; i < 16; ++i) v[i] = 0.f;
  return v;
}

// ---------------- conversions ----------------
__global__ void cvt_tok(const float* __restrict__ q, u16* __restrict__ qb,
                        const float* __restrict__ kv, u16* __restrict__ kvb,
                        const int* __restrict__ mask, float* __restrict__ madd2) {
  const int tid = threadIdx.x;
  const float* s = blockIdx.y ? kv : q;
  u16* d = blockIdx.y ? kvb : qb;
  const int i = blockIdx.x * 256 + tid;
  f32x4 v = ((const f32x4*)s)[i];
  u16x4 o;
  o[0] = f2bf(v[0]); o[1] = f2bf(v[1]); o[2] = f2bf(v[2]); o[3] = f2bf(v[3]);
  ((u16x4*)d)[i] = o;
  if (blockIdx.y == 0 && blockIdx.x < 16) {
    const int mi = blockIdx.x * 256 + tid;
    madd2[mi] = mask[mi] ? 0.f : NEGBIG;
  }
}

__global__ void cvt_w(const float* __restrict__ w0, u16* __restrict__ o0,
                      const float* __restrict__ w1, u16* __restrict__ o1,
                      const float* __restrict__ w2, u16* __restrict__ o2,
                      const float* __restrict__ w3, u16* __restrict__ o3) {
  const int y = blockIdx.y;
  const float* s = y == 0 ? w0 : y == 1 ? w1 : y == 2 ? w2 : w3;
  u16* d = y == 0 ? o0 : y == 1 ? o1 : y == 2 ? o2 : o3;
  const int i = blockIdx.x * 256 + threadIdx.x;
  f32x4 v = ((const f32x4*)s)[i];
  u16x4 o;
  o[0] = f2bf(v[0]); o[1] = f2bf(v[1]); o[2] = f2bf(v[2]); o[3] = f2bf(v[3]);
  ((u16x4*)d)[i] = o;
}

// ---------------- GEMM: C = A @ W^T + bias, M=4096 N=1024 K=1024 ----------------
struct Jobs {
  const u16* A[3];
  const u16* W[3];
  const float* bias[3];
  void* out[3];
  int mode[3];
};

__global__ __launch_bounds__(512, 4) void gemm8(Jobs jb) {
  const int z = blockIdx.z;
  const u16* __restrict__ A = jb.A[z];
  const u16* __restrict__ W = jb.W[z];
  const float* __restrict__ bias = jb.bias[z];
  void* __restrict__ out = jb.out[z];
  const int mode = jb.mode[z];

  __shared__ u16 smem[32768];  // [buf][ As 8192 | Bs 8192 ]; epilogue reuses as T[128][128]
  const int tid = threadIdx.x;
  const int w = tid >> 6, lane = tid & 63;
  const int wr = w >> 1, wc = w & 1;
  const int m0 = blockIdx.y * 128, n0 = blockIdx.x * 128;
  const int l15 = lane & 15, l4 = lane >> 4;
  const int srow = lane >> 3, sslot = lane & 7;

  f32x4 acc[2][4];
#pragma unroll
  for (int m = 0; m < 2; ++m)
#pragma unroll
    for (int n = 0; n < 4; ++n) acc[m][n] = (f32x4){0.f, 0.f, 0.f, 0.f};

  auto STAGE = [&](int buf, int k0) {
    u16* As = smem + buf * 16384;
    u16* Bs = As + 8192;
#pragma unroll
    for (int it = 0; it < 4; ++it) {
      const int rbase = (w & 3) * 32 + it * 8;
      const int r = rbase + srow;
      const int ca = ((sslot ^ (r & 7)) << 3);
      if (w < 4) g2l16(A + (size_t)(m0 + r) * 1024 + k0 + ca, &As[rbase * 64]);
      else       g2l16(W + (size_t)(n0 + r) * 1024 + k0 + ca, &Bs[rbase * 64]);
    }
  };

  STAGE(0, 0);
  __syncthreads();
  int cur = 0;
  for (int k0 = 0; k0 < 1024; k0 += 64) {
    if (k0 < 960) STAGE(cur ^ 1, k0 + 64);
    const u16* As = smem + cur * 16384;
    const u16* Bs = As + 8192;

    s16x8 af[2][2], bf[4][2];
#pragma unroll
    for (int m = 0; m < 2; ++m) {
      const int row = wr * 32 + m * 16 + l15;
#pragma unroll
      for (int kk = 0; kk < 2; ++kk) {
        const int slot = (kk * 4 + l4) ^ (row & 7);
        af[m][kk] = *(const s16x8*)&As[row * 64 + slot * 8];
      }
    }
#pragma unroll
    for (int n = 0; n < 4; ++n) {
      const int row = wc * 64 + n * 16 + l15;
#pragma unroll
      for (int kk = 0; kk < 2; ++kk) {
        const int slot = (kk * 4 + l4) ^ (row & 7);
        bf[n][kk] = *(const s16x8*)&Bs[row * 64 + slot * 8];
      }
    }
#pragma unroll
    for (int m = 0; m < 2; ++m)
#pragma unroll
      for (int n = 0; n < 4; ++n)
#pragma unroll
        for (int kk = 0; kk < 2; ++kk)
          acc[m][n] = __builtin_amdgcn_mfma_f32_16x16x32_bf16(af[m][kk], bf[n][kk],
                                                              acc[m][n], 0, 0, 0);
    __syncthreads();
    cur ^= 1;
  }

  if (mode != 1) {
#pragma unroll
    for (int n = 0; n < 4; ++n) {
      const int col = n0 + wc * 64 + n * 16 + l15;
      const float bv = bias[col];
#pragma unroll
      for (int m = 0; m < 2; ++m) {
        const int rowb = m0 + wr * 32 + m * 16 + l4 * 4;
#pragma unroll
        for (int j = 0; j < 4; ++j) {
          const float v = acc[m][n][j] + bv;
          if (mode == 2) ((float*)out)[(size_t)(rowb + j) * 1024 + col] = v;
          else           ((u16*)out)[(size_t)(rowb + j) * 1024 + col] = f2bf(v);
        }
      }
    }
  } else {
    u16* T = smem;  // [128 cols][128 rows], swizzled
#pragma unroll
    for (int n = 0; n < 4; ++n) {
      const int col = wc * 64 + n * 16 + l15;
      const float bv = bias[n0 + col];
#pragma unroll
      for (int m = 0; m < 2; ++m) {
        const int rowb = wr * 32 + m * 16 + l4 * 4;
        u16x4 v;
#pragma unroll
        for (int j = 0; j < 4; ++j) v[j] = f2bf(acc[m][n][j] + bv);
        *(u16x4*)&T[col * 128 + (rowb ^ ((col & 7) * 8))] = v;
      }
    }
    __syncthreads();
    u16* Vt = (u16*)out;
#pragma unroll
    for (int pass = 0; pass < 4; ++pass) {
      const int c = pass * 32 + (tid >> 4);
      const int slot = tid & 15;
      const s16x8 v = *(const s16x8*)&T[c * 128 + ((slot * 8) ^ ((c & 7) * 8))];
      const int cg = n0 + c, h = cg >> 6, d = cg & 63;
      const int rg = m0 + slot * 8, b = rg >> 11, rr = rg & 2047;
      *(s16x8*)&Vt[(((size_t)(b * 16 + h) * 64) + d) * 2048 + rr] = v;
    }
  }
}

// ---------------- Flash attention, 32x32 swapped MFMA, 2-wave blocks, dbuf ----------------
__global__ __launch_bounds__(128, 2) void attn_fwd(const u16* __restrict__ Qp,
                                                   const u16* __restrict__ Kp,
                                                   const u16* __restrict__ Vt,
                                                   const float* __restrict__ madd2,
                                                   u16* __restrict__ ctx) {
  __shared__ u16 smem[2][8192];  // [buf][ Ks 64x64 | Vs 64x64 ]
  __shared__ float mb[2][64];
  const int tid = threadIdx.x;
  const int w = tid >> 6, lane = tid & 63;
  const int l31 = lane & 31, h5 = lane >> 5;
  const int q0 = blockIdx.x * 64;
  const int head = blockIdx.y, b = blockIdx.z;
  const int srow = lane >> 3, sslot = lane & 7;

  // Q fragments (B operand): lane holds Q[q0+w*32+l31][head*64 + ks*16 + h5*8 + i]
  const u16* qbase = Qp + ((size_t)(b * 2048 + q0 + w * 32 + l31)) * 1024 + head * 64 + h5 * 8;
  s16x8 qf[4];
#pragma unroll
  for (int k = 0; k < 4; ++k) qf[k] = *(const s16x8*)(qbase + k * 16);

  f32x16 oa = z16(), ob = z16();
  float m2 = -__builtin_inff(), l_run = 0.f;

  auto STAGE = [&](int buf, int kv0) {
    u16* Ks = &smem[buf][0];
    u16* Vs = &smem[buf][4096];
#pragma unroll
    for (int it = 0; it < 4; ++it) {
      const int rbase = w * 32 + it * 8;
      const int r = rbase + srow;
      const int ca = ((sslot ^ (r & 7)) << 3);
      g2l16(Kp + (size_t)(b * 2048 + kv0 + r) * 1024 + head * 64 + ca, &Ks[rbase * 64]);
      g2l16(Vt + (((size_t)(b * 16 + head) * 64) + r) * 2048 + kv0 + ca, &Vs[rbase * 64]);
    }
    if (w == 0) g2l4(madd2 + b * 2048 + kv0 + lane, &mb[buf][0]);
  };

  STAGE(0, 0);
  __syncthreads();
  int cur = 0;

  for (int t = 0; t < 32; ++t) {
    if (t < 31) STAGE(cur ^ 1, (t + 1) * 64);
    const u16* Ks = &smem[cur][0];
    const u16* Vs = &smem[cur][4096];
    const float* mbc = &mb[cur][0];

    // S^T = K Q^T. Lane: q=l31; kv=(r&3)+8*(r>>2)+4*h5 (+32 for s1)
    f32x16 s0 = z16(), s1 = z16();
    __builtin_amdgcn_s_setprio(1);
#pragma unroll
    for (int ks = 0; ks < 4; ++ks) {
      const int cu = (ks * 16 + h5 * 8) ^ ((l31 & 7) * 8);
      const s16x8 kf0 = *(const s16x8*)&Ks[l31 * 64 + cu];
      const s16x8 kf1 = *(const s16x8*)&Ks[(32 + l31) * 64 + cu];
      s0 = __builtin_amdgcn_mfma_f32_32x32x16_bf16(kf0, qf[ks], s0, 0, 0, 0);
      s1 = __builtin_amdgcn_mfma_f32_32x32x16_bf16(kf1, qf[ks], s1, 0, 0, 0);
    }
    __builtin_amdgcn_s_setprio(0);

    // u = s*scale*log2e + mask (packed f32x2)
    f32x2 u2[16];
#pragma unroll
    for (int g = 0; g < 4; ++g)
#pragma unroll
      for (int e2 = 0; e2 < 2; ++e2) {
        const int j = g * 2 + e2;
        const f32x2 mk0 = *(const f32x2*)&mbc[g * 8 + h5 * 4 + e2 * 2];
        const f32x2 mk1 = *(const f32x2*)&mbc[32 + g * 8 + h5 * 4 + e2 * 2];
        f32x2 sa, sb;
        sa[0] = s0[g * 4 + e2 * 2]; sa[1] = s0[g * 4 + e2 * 2 + 1];
        sb[0] = s1[g * 4 + e2 * 2]; sb[1] = s1[g * 4 + e2 * 2 + 1];
        u2[j] = sa * C_SCALE + mk0;
        u2[8 + j] = sb * C_SCALE + mk1;
      }

    // row max: in-lane tree + one cross-half exchange
    float tm[8];
#pragma unroll
    for (int i = 0; i < 8; ++i) {
      const f32x2 a = u2[i], c = u2[i + 8];
      tm[i] = fmaxf(fmaxf(a[0], a[1]), fmaxf(c[0], c[1]));
    }
#pragma unroll
    for (int i = 0; i < 4; ++i) tm[i] = fmaxf(tm[i], tm[i + 4]);
    float mx = fmaxf(fmaxf(tm[0], tm[1]), fmaxf(tm[2], tm[3]));
    mx = fmaxf(mx, __shfl_xor(mx, 32, 64));

    if (__any(mx > m2 + THR2)) {
      const float mnew = fmaxf(m2, mx);
      const float alpha = exp2_fast(m2 - mnew);
      m2 = mnew;
      l_run *= alpha;
      oa *= alpha;
      ob *= alpha;
    }

    f32x2 p2[16];
    const float nm2 = -m2;
#pragma unroll
    for (int i = 0; i < 16; ++i) {
      const f32x2 d = u2[i] + nm2;
      f32x2 e;
      e[0] = exp2_fast(d[0]);
      e[1] = exp2_fast(d[1]);
      p2[i] = e;
    }

    // row sum (packed tree)
    f32x2 s2t[8];
#pragma unroll
    for (int i = 0; i < 8; ++i) s2t[i] = p2[i] + p2[i + 8];
#pragma unroll
    for (int i = 0; i < 4; ++i) s2t[i] = s2t[i] + s2t[i + 4];
    const f32x2 sfin = (s2t[0] + s2t[1]) + (s2t[2] + s2t[3]);
    float ps = sfin[0] + sfin[1];
    ps += __shfl_xor(ps, 32, 64);
    l_run += ps;

    // P -> bf16 B-fragments via cvt_pk + permlane32_swap (T12)
    u32 pk[16];
#pragma unroll
    for (int j = 0; j < 16; ++j) {
      u32 d;
      asm("v_cvt_pk_bf16_f32 %0, %1, %2" : "=v"(d) : "v"(p2[j][0]), "v"(p2[j][1]));
      pk[j] = d;
    }
    s16x8 pf[4];
#pragma unroll
    for (int kvb = 0; kvb < 2; ++kvb)
#pragma unroll
      for (int gp = 0; gp < 2; ++gp) {
        u32 a0 = pk[kvb * 8 + gp * 4 + 0], a1 = pk[kvb * 8 + gp * 4 + 1];
        u32 b0 = pk[kvb * 8 + gp * 4 + 2], b1 = pk[kvb * 8 + gp * 4 + 3];
        asm("v_permlane32_swap_b32 %0, %1" : "+v"(a0), "+v"(b0));
        asm("v_permlane32_swap_b32 %0, %1" : "+v"(a1), "+v"(b1));
        u32x4 fv; fv[0] = a0; fv[1] = a1; fv[2] = b0; fv[3] = b1;
        pf[kvb * 2 + gp] = __builtin_bit_cast(s16x8, fv);
      }

    // O^T += V^T P
    __builtin_amdgcn_s_setprio(1);
#pragma unroll
    for (int ks = 0; ks < 4; ++ks) {
      const int cu = (ks * 16 + h5 * 8) ^ ((l31 & 7) * 8);
      const s16x8 vf0 = *(const s16x8*)&Vs[l31 * 64 + cu];
      const s16x8 vf1 = *(const s16x8*)&Vs[(32 + l31) * 64 + cu];
      oa = __builtin_amdgcn_mfma_f32_32x32x16_bf16(vf0, pf[ks], oa, 0, 0, 0);
      ob = __builtin_amdgcn_mfma_f32_32x32x16_bf16(vf1, pf[ks], ob, 0, 0, 0);
    }
    __builtin_amdgcn_s_setprio(0);

    __syncthreads();
    cur ^= 1;
  }

  // epilogue: normalize, transpose via wave-private LDS, coalesced stores
  const float inv = 1.f / l_run;
  u16* Ot = &smem[0][w * 2048];  // [32 q][64 d], swizzled
#pragma unroll
  for (int dblk = 0; dblk < 2; ++dblk)
#pragma unroll
    for (int g = 0; g < 4; ++g) {
      u16x4 v;
#pragma unroll
      for (int e = 0; e < 4; ++e)
        v[e] = f2bf((dblk ? ob[g * 4 + e] : oa[g * 4 + e]) * inv);
      *(u16x4*)&Ot[l31 * 64 + ((dblk * 32 + g * 8 + h5 * 4) ^ ((l31 & 7) * 8))] = v;
    }
#pragma unroll
  for (int pass = 0; pass < 4; ++pass) {
    const int row = pass * 8 + srow;
    const s16x8 v = *(const s16x8*)&Ot[row * 64 + ((sslot * 8) ^ ((row & 7) * 8))];
    *(s16x8*)(ctx + ((size_t)(b * 2048 + q0 + w * 32 + row)) * 1024 + head * 64 + sslot * 8) = v;
  }
}

extern "C" void kernel_launch(void* const* d_in, const int* in_sizes, int n_in,
                              void* d_out, int out_size, void* d_ws, size_t ws_size,
                              hipStream_t stream) {
  const float* query = (const float*)d_in[0];
  const float* keyv = (const float*)d_in[1];
  const int* mask = (const int*)d_in[2];
  const float* Wq = (const float*)d_in[3];
  const float* bq = (const float*)d_in[4];
  const float* Wk = (const float*)d_in[5];
  const float* bk = (const float*)d_in[6];
  const float* Wv = (const float*)d_in[7];
  const float* bv = (const float*)d_in[8];
  const float* Wo = (const float*)d_in[9];
  const float* bo = (const float*)d_in[10];

  const size_t NTOK = (size_t)4096 * 1024;
  const size_t NW = (size_t)1024 * 1024;
  u16* p = (u16*)d_ws;
  u16* qb = p;  p += NTOK;
  u16* kvb = p; p += NTOK;
  u16* wqb = p; p += NW;
  u16* wkb = p; p += NW;
  u16* wvb = p; p += NW;
  u16* wob = p; p += NW;
  u16* Qp = p;  p += NTOK;
  u16* Kp = p;  p += NTOK;
  u16* Vt = p;  p += NTOK;
  u16* ctx = p; p += NTOK;
  float* madd2 = (float*)p;  // 4096 f32

  cvt_tok<<<dim3(4096, 2), 256, 0, stream>>>(query, qb, keyv, kvb, mask, madd2);
  cvt_w<<<dim3(1024, 4), 256, 0, stream>>>(Wq, wqb, Wk, wkb, Wv, wvb, Wo, wob);

  Jobs pj;
  pj.A[0] = qb;  pj.W[0] = wqb; pj.bias[0] = bq; pj.out[0] = Qp; pj.mode[0] = 0;
  pj.A[1] = kvb; pj.W[1] = wkb; pj.bias[1] = bk; pj.out[1] = Kp; pj.mode[1] = 0;
  pj.A[2] = kvb; pj.W[2] = wvb; pj.bias[2] = bv; pj.out[2] = Vt; pj.mode[2] = 1;
  gemm8<<<dim3(8, 32, 3), 512, 0, stream>>>(pj);

  attn_fwd<<<dim3(32, 16, 2), 128, 0, stream>>>(Qp, Kp, Vt, madd2, ctx);

  Jobs oj;
  oj.A[0] = ctx; oj.W[0] = wob; oj.bias[0] = bo; oj.out[0] = d_out; oj.mode[0] = 2;
  oj.A[1] = ctx; oj.W[1] = wob; oj.bias[1] = bo; oj.out[1] = d_out; oj.mode[1] = 2;
  oj.A[2] = ctx; oj.W[2] = wob; oj.bias[2] = bo; oj.out[2] = d_out; oj.mode[2] = 2;
  gemm8<<<dim3(8, 32, 1), 512, 0, stream>>>(oj);
}